// Round 11
// baseline (554.930 us; speedup 1.0000x reference)
//
#include <hip/hip_runtime.h>

#define B_ 32
#define T_ 400
#define C_ 3000
#define SN_ 128
#define SD_ 512
#define LN120 4.78749174f  // ln(120) = ln(8*15): loop scale constant
#define LNU 2.70805020f    // ln(15): final normalizer
#define SPANB 48           // byte stride between 32-byte spans in LDS (disjoint banks)

__device__ __forceinline__ float clip30(float v) { return fminf(30.f, fmaxf(-30.f, v)); }

// unsigned 8x4-bit dot: d = c + sum_i a.nib[i]*b.nib[i]
__device__ __forceinline__ int dot8u4(unsigned a, unsigned b, int c) {
#if __has_builtin(__builtin_amdgcn_udot8)
    return (int)__builtin_amdgcn_udot8(a, b, (unsigned)c, false);
#else
    int r = c;
    #pragma unroll
    for (int i = 0; i < 8; ++i)
        r += (int)((a >> (4 * i)) & 0xF) * (int)((b >> (4 * i)) & 0xF);
    return r;
#endif
}

template <int CTRL>
__device__ __forceinline__ int dpp_i(int v) {
    return __builtin_amdgcn_update_dpp(v, v, CTRL, 0xF, 0xF, false);
}
template <int CTRL>
__device__ __forceinline__ float fmaxdpp(float v) {
    int mv = __builtin_amdgcn_update_dpp(__float_as_int(v), __float_as_int(v), CTRL, 0xF, 0xF, false);
    return fmaxf(v, __int_as_float(mv));
}
template <int CTRL>
__device__ __forceinline__ float faddpp(float v) {
    int mv = __builtin_amdgcn_update_dpp(__float_as_int(v), __float_as_int(v), CTRL, 0xF, 0xF, false);
    return v + __int_as_float(mv);
}
// a += partner-lane's b; quad_perm xor1=0xB1 xor2=0x4E; 0x12n = xor_n (gfx950, proven R2)
template <int CTRL>
__device__ __forceinline__ float fxaddf(float a, float b) {
    int t = __builtin_amdgcn_update_dpp(__float_as_int(b), __float_as_int(b), CTRL, 0xF, 0xF, false);
    return a + __int_as_float(t);
}
__device__ __forceinline__ float swz16f(float v) {
    return __int_as_float(__builtin_amdgcn_ds_swizzle(__float_as_int(v), 0x401F));
}
// wave-wide max, VALU-only: 4 xor-DPP stages + 4 readlanes + 3 maxes. (proven R3)
__device__ __forceinline__ float wavemax_fast(float v) {
    v = fmaxdpp<0x121>(v); v = fmaxdpp<0x122>(v);
    v = fmaxdpp<0x124>(v); v = fmaxdpp<0x128>(v);
    float a = __int_as_float(__builtin_amdgcn_readlane(__float_as_int(v), 0));
    float b = __int_as_float(__builtin_amdgcn_readlane(__float_as_int(v), 16));
    float c = __int_as_float(__builtin_amdgcn_readlane(__float_as_int(v), 32));
    float d = __int_as_float(__builtin_amdgcn_readlane(__float_as_int(v), 48));
    return fmaxf(fmaxf(a, b), fmaxf(c, d));
}
__device__ __forceinline__ float waveallsum(float v) {
    v = faddpp<0x121>(v); v = faddpp<0x122>(v);
    v = faddpp<0x124>(v); v = faddpp<0x128>(v);
    v = v + swz16f(v);
    v = v + __shfl_xor(v, 32, 64);
    return v;
}
// workgroup barrier with LDS-only drain (keeps em prefetch in flight). (proven R4)
__device__ __forceinline__ void barrier_lds() {
    asm volatile("s_waitcnt lgkmcnt(0)\n\ts_barrier" ::: "memory");
}

// prep: unchanged from R10.
//  [0,32768) dwords: exp(den_trans) u4 (scale 8, clamp 15), dot8 span layout.
//  [32768,+6553600): den emissions LINEAR: E = exp(clip(x)).
//  then em_num[b][t][s] pre-clipped log-domain.
__global__ void prep(const float* __restrict__ dt, unsigned* __restrict__ tp8,
                     const float* __restrict__ x, const int* __restrict__ den_pdf,
                     const int* __restrict__ num_pdf,
                     float* __restrict__ em_den, float* __restrict__ em_num) {
    size_t id = (size_t)blockIdx.x * 1024 + threadIdx.x;
    if (id < 32768) {
        int o = (int)id;
        int b4 = o & 3, tid = (o >> 2) & 511, k = o >> 11;
        int r = 4 * k + b4;
        int m = r >> 3, i = r & 7;
        int g = tid >> 3, j = tid & 7;
        int s_out = 8 * g + (m ^ j);
        int src0 = 64 * j + 8 * i;
        unsigned wv = 0;
        #pragma unroll
        for (int nb = 0; nb < 8; ++nb) {
            float e = __expf(dt[(src0 + nb) * SD_ + s_out]);
            int pq = __float2int_rn(e * 8.f);
            if (pq > 15) pq = 15;
            wv |= (unsigned)pq << (4 * nb);
        }
        tp8[o] = wv;
    } else if (id < 32768 + 6553600) {
        size_t e = id - 32768;
        int s = (int)(e & 511);
        size_t bt = e >> 9;                    // b*400 + t
        em_den[e] = __expf(clip30(x[bt * C_ + den_pdf[s]]));   // LINEAR domain
    } else if (id < 32768 + 6553600 + 1638400) {
        size_t e = id - 32768 - 6553600;
        int s = (int)(e & 127);
        size_t bt = e >> 7;
        int b = (int)(bt / 400);
        em_num[e] = clip30(x[bt * C_ + num_pdf[b * SN_ + s]]);
    }
}

// 1024-thread WG: waves 0-7 = batch A, waves 8-15 = batch B — two independent
// R10-identical den recursions sharing one barrier. 4 waves/SIMD: the two
// batches' stall windows (LDS latency, DPP chains, barrier skew) overlap in
// wall time instead of being paid once per batch.
__global__ __launch_bounds__(1024, 1)
void fwd_kernel(const int* __restrict__ seqlen,
                const float* __restrict__ num_trans,
                const float* __restrict__ num_init, const float* __restrict__ num_final,
                const unsigned* __restrict__ tp8,
                const float* __restrict__ den_init, const float* __restrict__ den_final,
                const float* __restrict__ em_den, const float* __restrict__ em_num,
                float* __restrict__ parts) {
    const int tid = threadIdx.x;

    if (blockIdx.x < 16) {
        __shared__ __align__(16) unsigned char ea[2][2][8 * SPANB];  // [bat][buf][spans]
        __shared__ float Ms[2][2][8];                                // [bat][buf][wave]
        __shared__ float fr[2][8];
        const int bb = blockIdx.x;
        const int w = tid >> 6, l = tid & 63;   // wave 0..15, lane
        const int bat = w >> 3, wb = w & 7;     // batch half, wave-within-batch
        const int j = tid & 7;                  // source span (0..7)
        const int st = tid & 511;               // state
        const int b = 2 * bb + bat;
        const int L = seqlen[b];
        const int Lmax = max(seqlen[2 * bb], seqlen[2 * bb + 1]);

        // trans: slot m, chunk i -> tq[8m+i] = T4[64j+8i+nb, 8g+(m^j)] nibbles
        // (same table for both batches)
        unsigned tq[64];
        {
            const uint4* tg = (const uint4*)tp8;
            #pragma unroll
            for (int i = 0; i < 16; ++i) {
                uint4 v = tg[(i << 9) + st];
                tq[4 * i + 0] = v.x;
                tq[4 * i + 1] = v.y;
                tq[4 * i + 2] = v.z;
                tq[4 * i + 3] = v.w;
            }
        }

        const float* emp = em_den + (size_t)b * T_ * SD_ + st;

        // nibble pack + write: lane (tid&7)==0 writes 8 states' nibbles per dword
        #define NPACK(UN, BUF) { \
            int uu = (UN); \
            uu |= dpp_i<0xB1>(uu) << 4; \
            uu |= dpp_i<0x4E>(uu) << 8; \
            uu |= dpp_i<0x124>(uu) << 16; \
            if ((tid & 7) == 0) \
                *(unsigned*)&ea[bat][(BUF)][SPANB * wb + ((tid & 63) >> 1)] = (unsigned)uu; }

        // t = 0: alpha0_lin = exp(den_init)*E0; quantize vs exact wave max (scale 15)
        float a0lin = __expf(den_init[st]) * emp[0];
        float K0 = wavemax_fast(a0lin);
        int un = __float2int_rn(15.f * a0lin * __builtin_amdgcn_rcpf(K0));
        float ms_w = __logf(K0);                 // own wave's log scale, in register
        NPACK(un, 0)
        if (l == 0) Ms[bat][0][wb] = ms_w;
        barrier_lds();

        float EA = emp[SD_], EB = emp[2 * SD_];  // linear-domain emission prefetch
        int cur = 0;
        for (int t = 1; t < Lmax; ++t) {
            int tn = (t + 2 < L) ? t + 2 : L - 1;
            float EN = emp[(size_t)tn * SD_];

            float ms_j = Ms[bat][cur][j];       // source span's scale (LDS; own in reg)
            const uint4* er = (const uint4*)&ea[bat][cur][SPANB * j];
            uint4 e0 = er[0], e1 = er[1];

            int ac0, ac1, ac2, ac3, ac4, ac5, ac6, ac7;
            #define DOTD0(W, I) \
                ac0 = dot8u4((W), tq[(I)],      0); \
                ac1 = dot8u4((W), tq[8 + (I)],  0); \
                ac2 = dot8u4((W), tq[16 + (I)], 0); \
                ac3 = dot8u4((W), tq[24 + (I)], 0); \
                ac4 = dot8u4((W), tq[32 + (I)], 0); \
                ac5 = dot8u4((W), tq[40 + (I)], 0); \
                ac6 = dot8u4((W), tq[48 + (I)], 0); \
                ac7 = dot8u4((W), tq[56 + (I)], 0);
            #define DOTD(W, I) \
                ac0 = dot8u4((W), tq[(I)],      ac0); \
                ac1 = dot8u4((W), tq[8 + (I)],  ac1); \
                ac2 = dot8u4((W), tq[16 + (I)], ac2); \
                ac3 = dot8u4((W), tq[24 + (I)], ac3); \
                ac4 = dot8u4((W), tq[32 + (I)], ac4); \
                ac5 = dot8u4((W), tq[40 + (I)], ac5); \
                ac6 = dot8u4((W), tq[48 + (I)], ac6); \
                ac7 = dot8u4((W), tq[56 + (I)], ac7);
            DOTD0(e0.x, 0) DOTD(e0.y, 1) DOTD(e0.z, 2) DOTD(e0.w, 3)
            DOTD(e1.x, 4)  DOTD(e1.y, 5) DOTD(e1.z, 6) DOTD(e1.w, 7)
            #undef DOTD
            #undef DOTD0

            // scale by own span's factor, then select-free XOR butterfly fold (all DPP)
            float e_own = __expf(ms_j - ms_w);
            float f0 = (float)ac0 * e_own, f1 = (float)ac1 * e_own;
            float f2 = (float)ac2 * e_own, f3 = (float)ac3 * e_own;
            float f4 = (float)ac4 * e_own, f5 = (float)ac5 * e_own;
            float f6 = (float)ac6 * e_own, f7 = (float)ac7 * e_own;
            f0 = fxaddf<0xB1>(f0, f1);  f2 = fxaddf<0xB1>(f2, f3);
            f4 = fxaddf<0xB1>(f4, f5);  f6 = fxaddf<0xB1>(f6, f7);
            f0 = fxaddf<0x4E>(f0, f2);  f4 = fxaddf<0x4E>(f4, f6);
            f0 = fxaddf<0x124>(f0, f4); // xor4 via DPP (proven on gfx950 by R2)

            // linear tail: Kv = f0*E; exact wave max; un = 15*Kv/K (<=15 by constr.)
            float Kv = f0 * EA;
            float K = wavemax_fast(Kv);
            int nun = __float2int_rn(15.f * Kv * __builtin_amdgcn_rcpf(K));
            if (t < L) {                         // freeze shorter batch (R6-proven)
                un = nun;
                ms_w = ms_w + __logf(K) - LN120; // product scale 8*15 = 120
            }
            NPACK(un, cur ^ 1)                   // frozen value re-written each step
            if (l == 0) Ms[bat][cur ^ 1][wb] = ms_w;
            EA = EB; EB = EN;
            barrier_lds();              // single shared barrier/step (both batches)
            cur ^= 1;
        }
        #undef NPACK

        // final: alpha(s) = log(u_s/15) + Ms[w(s)]
        float mm = Ms[bat][cur][0];
        #pragma unroll
        for (int k2 = 1; k2 < 8; ++k2) mm = fmaxf(mm, Ms[bat][cur][k2]);
        float fv = (float)un * __expf(den_final[st] + (ms_w - mm));
        fv = waveallsum(fv);
        if (l == 0) fr[bat][wb] = fv;
        __syncthreads();
        if ((tid & 511) == 0) {                  // tid 0 -> batch A, tid 512 -> batch B
            float tot = 0.f;
            for (int i = 0; i < 8; ++i) tot += fr[bat][i];
            parts[B_ + b] = mm + __logf(tot) - LNU;
        }
    } else {
        // ---- numerator: 8 banded 128-state chains per 1024-thread WG
        //      (R2-proven structure; double-buffered -> 1 barrier/step) ----
        __shared__ float aLn[2][8][SN_];
        __shared__ float nredn[8][2];
        const int nb = blockIdx.x - 16;               // 0..3
        const int lb = tid >> 7;                      // local batch 0..7
        const int b  = nb * 8 + lb;
        const int s  = tid & 127;
        const int L  = seqlen[b];
        const int lane = tid & 63;
        const int wv2 = (tid >> 6) & 1;
        const float* ep = em_num + (size_t)b * T_ * SN_ + s;
        const float tself = num_trans[((size_t)b * SN_ + s) * SN_ + s];
        const float tup = (s > 0) ? num_trans[((size_t)b * SN_ + (s - 1)) * SN_ + s] : 0.f;
        float alpha = num_init[b * SN_ + s] + ep[0];
        aLn[0][lb][s] = alpha;
        __syncthreads();
        float emA = ep[SN_], emB = ep[2 * SN_];
        int cur = 0;
        for (int t = 1; t < T_; ++t) {
            int tt = t + 2; if (tt > T_ - 1) tt = T_ - 1;
            float emN = ep[(size_t)tt * SN_];
            bool live = (t < L);
            float yy = alpha + tself;
            float newa;
            if (s > 0) {
                float xx = aLn[cur][lb][s - 1] + tup;
                float mx = fmaxf(xx, yy), mn = fminf(xx, yy);
                newa = mx + log1pf(__expf(mn - mx)) + emA;
            } else {
                newa = yy + emA;
            }
            if (live) alpha = newa;
            aLn[cur ^ 1][lb][s] = alpha;
            emA = emB; emB = emN;
            __syncthreads();
            cur ^= 1;
        }
        float v = alpha + num_final[b * SN_ + s];
        float wm = v;
        #pragma unroll
        for (int o = 32; o; o >>= 1) wm = fmaxf(wm, __shfl_xor(wm, o, 64));
        if (lane == 0) nredn[lb][wv2] = wm;
        __syncthreads();
        float fm = fmaxf(nredn[lb][0], nredn[lb][1]);
        __syncthreads();
        float pe = __expf(v - fm);
        #pragma unroll
        for (int o = 32; o; o >>= 1) pe += __shfl_xor(pe, o, 64);
        if (lane == 0) nredn[lb][wv2] = pe;
        __syncthreads();
        if (s == 0) parts[b] = fm + __logf(nredn[lb][0] + nredn[lb][1]);
    }
}

__global__ void finish(const float* __restrict__ parts, float* __restrict__ out) {
    int lane = threadIdx.x;   // 64 threads, 1 wave
    float v = (lane < B_) ? (parts[B_ + lane] - parts[lane]) : 0.f;
    #pragma unroll
    for (int o = 32; o; o >>= 1) v += __shfl_xor(v, o, 64);
    if (lane == 0) out[0] = v;   // loss = sum(den) - sum(num)
}

extern "C" void kernel_launch(void* const* d_in, const int* in_sizes, int n_in,
                              void* d_out, int out_size, void* d_ws, size_t ws_size,
                              hipStream_t stream) {
    const float* x         = (const float*)d_in[0];
    const int*   seqlen    = (const int*)d_in[1];
    const float* num_trans = (const float*)d_in[2];
    const int*   num_pdf   = (const int*)d_in[3];
    const float* num_init  = (const float*)d_in[4];
    const float* num_final = (const float*)d_in[5];
    const float* den_trans = (const float*)d_in[6];
    const int*   den_pdf   = (const int*)d_in[7];
    const float* den_init  = (const float*)d_in[8];
    const float* den_final = (const float*)d_in[9];
    float* out   = (float*)d_out;
    float* parts = (float*)d_ws;                                  // 64 floats
    unsigned* tp8 = (unsigned*)((char*)d_ws + 4096);              // 128 KB u4 packed trans
    float* em_den = (float*)((char*)d_ws + 4096 + 131072);        // 26.2 MB (linear E)
    float* em_num = em_den + 6553600;                             // 6.5 MB

    prep<<<8032, 1024, 0, stream>>>(den_trans, tp8, x, den_pdf, num_pdf, em_den, em_num);
    fwd_kernel<<<20, 1024, 0, stream>>>(seqlen, num_trans, num_init, num_final,
                                        tp8, den_init, den_final, em_den, em_num, parts);
    finish<<<1, 64, 0, stream>>>(parts, out);
}

// Round 12
// 330.431 us; speedup vs baseline: 1.6794x; 1.6794x over previous
//
#include <hip/hip_runtime.h>

#define B_ 32
#define T_ 400
#define C_ 3000
#define SN_ 128
#define SD_ 512
#define LN120 4.78749174f  // ln(120) = ln(8*15): loop scale constant
#define LNU 2.70805020f    // ln(15): final normalizer
#define SPANB 48           // byte stride between 32-byte spans in LDS (disjoint banks)

__device__ __forceinline__ float clip30(float v) { return fminf(30.f, fmaxf(-30.f, v)); }

// unsigned 8x4-bit dot: d = c + sum_i a.nib[i]*b.nib[i]
__device__ __forceinline__ int dot8u4(unsigned a, unsigned b, int c) {
#if __has_builtin(__builtin_amdgcn_udot8)
    return (int)__builtin_amdgcn_udot8(a, b, (unsigned)c, false);
#else
    int r = c;
    #pragma unroll
    for (int i = 0; i < 8; ++i)
        r += (int)((a >> (4 * i)) & 0xF) * (int)((b >> (4 * i)) & 0xF);
    return r;
#endif
}

template <int CTRL>
__device__ __forceinline__ int dpp_i(int v) {
    return __builtin_amdgcn_update_dpp(v, v, CTRL, 0xF, 0xF, false);
}
template <int CTRL>
__device__ __forceinline__ float fmaxdpp(float v) {
    int mv = __builtin_amdgcn_update_dpp(__float_as_int(v), __float_as_int(v), CTRL, 0xF, 0xF, false);
    return fmaxf(v, __int_as_float(mv));
}
template <int CTRL>
__device__ __forceinline__ float faddpp(float v) {
    int mv = __builtin_amdgcn_update_dpp(__float_as_int(v), __float_as_int(v), CTRL, 0xF, 0xF, false);
    return v + __int_as_float(mv);
}
// a += partner-lane's b; quad_perm xor1=0xB1 xor2=0x4E; 0x12n = xor_n (gfx950, proven R2)
template <int CTRL>
__device__ __forceinline__ float fxaddf(float a, float b) {
    int t = __builtin_amdgcn_update_dpp(__float_as_int(b), __float_as_int(b), CTRL, 0xF, 0xF, false);
    return a + __int_as_float(t);
}
__device__ __forceinline__ float swz16f(float v) {
    return __int_as_float(__builtin_amdgcn_ds_swizzle(__float_as_int(v), 0x401F));
}
// wave-wide max, VALU-only: 4 xor-DPP stages + 4 readlanes + 3 maxes. (proven R3)
__device__ __forceinline__ float wavemax_fast(float v) {
    v = fmaxdpp<0x121>(v); v = fmaxdpp<0x122>(v);
    v = fmaxdpp<0x124>(v); v = fmaxdpp<0x128>(v);
    float a = __int_as_float(__builtin_amdgcn_readlane(__float_as_int(v), 0));
    float b = __int_as_float(__builtin_amdgcn_readlane(__float_as_int(v), 16));
    float c = __int_as_float(__builtin_amdgcn_readlane(__float_as_int(v), 32));
    float d = __int_as_float(__builtin_amdgcn_readlane(__float_as_int(v), 48));
    return fmaxf(fmaxf(a, b), fmaxf(c, d));
}
__device__ __forceinline__ float waveallsum(float v) {
    v = faddpp<0x121>(v); v = faddpp<0x122>(v);
    v = faddpp<0x124>(v); v = faddpp<0x128>(v);
    v = v + swz16f(v);
    v = v + __shfl_xor(v, 32, 64);
    return v;
}
// workgroup barrier with LDS-only drain (keeps em prefetch in flight). (proven R4)
__device__ __forceinline__ void barrier_lds() {
    asm volatile("s_waitcnt lgkmcnt(0)\n\ts_barrier" ::: "memory");
}

// prep: unchanged from R10.
//  [0,32768) dwords: exp(den_trans) u4 (scale 8, clamp 15), dot8 span layout.
//  [32768,+6553600): den emissions LINEAR: E = exp(clip(x)).
//  then em_num[b][t][s] pre-clipped log-domain.
__global__ void prep(const float* __restrict__ dt, unsigned* __restrict__ tp8,
                     const float* __restrict__ x, const int* __restrict__ den_pdf,
                     const int* __restrict__ num_pdf,
                     float* __restrict__ em_den, float* __restrict__ em_num) {
    size_t id = (size_t)blockIdx.x * 1024 + threadIdx.x;
    if (id < 32768) {
        int o = (int)id;
        int b4 = o & 3, tid = (o >> 2) & 511, k = o >> 11;
        int r = 4 * k + b4;
        int m = r >> 3, i = r & 7;
        int g = tid >> 3, j = tid & 7;
        int s_out = 8 * g + (m ^ j);
        int src0 = 64 * j + 8 * i;
        unsigned wv = 0;
        #pragma unroll
        for (int nb = 0; nb < 8; ++nb) {
            float e = __expf(dt[(src0 + nb) * SD_ + s_out]);
            int pq = __float2int_rn(e * 8.f);
            if (pq > 15) pq = 15;
            wv |= (unsigned)pq << (4 * nb);
        }
        tp8[o] = wv;
    } else if (id < 32768 + 6553600) {
        size_t e = id - 32768;
        int s = (int)(e & 511);
        size_t bt = e >> 9;                    // b*400 + t
        em_den[e] = __expf(clip30(x[bt * C_ + den_pdf[s]]));   // LINEAR domain
    } else if (id < 32768 + 6553600 + 1638400) {
        size_t e = id - 32768 - 6553600;
        int s = (int)(e & 127);
        size_t bt = e >> 7;
        int b = (int)(bt / 400);
        em_num[e] = clip30(x[bt * C_ + num_pdf[b * SN_ + s]]);
    }
}

// amdgpu_agpr_alloc(0): forbid AGPR allocation (LLVM "amdgpu-agpr-alloc"=0).
// Three prior probes (R4 plain array, R5 asm "v" constraints, R7 launch_bounds
// 512-reg budget) all left tq AGPR-parked with a v_accvgpr_read per dot
// (~256 cyc/step of 1716). If clang doesn't know the attribute it's a warning
// and this binary is bit-identical to R10.
__attribute__((amdgpu_agpr_alloc(0)))
__global__ __launch_bounds__(512, 1)
void fwd_kernel(const int* __restrict__ seqlen,
                const float* __restrict__ num_trans,
                const float* __restrict__ num_init, const float* __restrict__ num_final,
                const unsigned* __restrict__ tp8,
                const float* __restrict__ den_init, const float* __restrict__ den_final,
                const float* __restrict__ em_den, const float* __restrict__ em_num,
                float* __restrict__ parts) {
    const int tid = threadIdx.x;

    if (blockIdx.x < B_) {
        // ---- denominator: one batch/WG, 512 threads, 1 state/thread.
        // u4 activations (scale 15) x u4 trans (scale 8) via v_dot8: 64 dots/thread,
        // tq = 64 dwords, 2 b128 LDS reads/step. Per-wave log-scales Ms[w];
        // one barrier/step; XOR-DPP fold + nibble pack. (R10-proven) ----
        __shared__ __align__(16) unsigned char ea[2][8 * SPANB];  // u4 acts, dbuf (32B/span)
        __shared__ float Ms[2][8];                                // per-wave log scales
        __shared__ float fr[8];
        const int b = blockIdx.x;
        const int L = seqlen[b];
        const int w = tid >> 6, l = tid & 63;   // wave, lane
        const int j = tid & 7;                  // source span (0..7)

        // trans: slot m, chunk i -> tq[8m+i] = T4[64j+8i+nb, 8g+(m^j)] nibbles
        unsigned tq[64];
        {
            const uint4* tg = (const uint4*)tp8;
            #pragma unroll
            for (int i = 0; i < 16; ++i) {
                uint4 v = tg[(i << 9) + tid];
                tq[4 * i + 0] = v.x;
                tq[4 * i + 1] = v.y;
                tq[4 * i + 2] = v.z;
                tq[4 * i + 3] = v.w;
            }
        }

        const float* emp = em_den + (size_t)b * T_ * SD_ + tid;

        // nibble pack + write: lane (tid&7)==0 writes 8 states' nibbles per dword
        #define NPACK(UN, BUF) { \
            int uu = (UN); \
            uu |= dpp_i<0xB1>(uu) << 4; \
            uu |= dpp_i<0x4E>(uu) << 8; \
            uu |= dpp_i<0x124>(uu) << 16; \
            if ((tid & 7) == 0) \
                *(unsigned*)&ea[(BUF)][SPANB * w + ((tid & 63) >> 1)] = (unsigned)uu; }

        // t = 0: alpha0_lin = exp(den_init)*E0; quantize vs exact wave max (scale 15)
        float a0lin = __expf(den_init[tid]) * emp[0];
        float K0 = wavemax_fast(a0lin);
        int un = __float2int_rn(15.f * a0lin * __builtin_amdgcn_rcpf(K0));
        float ms_w = __logf(K0);                 // own wave's log scale, in register
        NPACK(un, 0)
        if (l == 0) Ms[0][w] = ms_w;
        barrier_lds();

        float EA = emp[SD_], EB = emp[2 * SD_];  // linear-domain emission prefetch
        int cur = 0;
        for (int t = 1; t < L; ++t) {
            int tn = (t + 2 < L) ? t + 2 : L - 1;
            float EN = emp[(size_t)tn * SD_];

            float ms_j = Ms[cur][j];            // source span's scale (LDS; own in reg)
            const uint4* er = (const uint4*)&ea[cur][SPANB * j];
            uint4 e0 = er[0], e1 = er[1];

            int ac0, ac1, ac2, ac3, ac4, ac5, ac6, ac7;
            #define DOTD0(W, I) \
                ac0 = dot8u4((W), tq[(I)],      0); \
                ac1 = dot8u4((W), tq[8 + (I)],  0); \
                ac2 = dot8u4((W), tq[16 + (I)], 0); \
                ac3 = dot8u4((W), tq[24 + (I)], 0); \
                ac4 = dot8u4((W), tq[32 + (I)], 0); \
                ac5 = dot8u4((W), tq[40 + (I)], 0); \
                ac6 = dot8u4((W), tq[48 + (I)], 0); \
                ac7 = dot8u4((W), tq[56 + (I)], 0);
            #define DOTD(W, I) \
                ac0 = dot8u4((W), tq[(I)],      ac0); \
                ac1 = dot8u4((W), tq[8 + (I)],  ac1); \
                ac2 = dot8u4((W), tq[16 + (I)], ac2); \
                ac3 = dot8u4((W), tq[24 + (I)], ac3); \
                ac4 = dot8u4((W), tq[32 + (I)], ac4); \
                ac5 = dot8u4((W), tq[40 + (I)], ac5); \
                ac6 = dot8u4((W), tq[48 + (I)], ac6); \
                ac7 = dot8u4((W), tq[56 + (I)], ac7);
            DOTD0(e0.x, 0) DOTD(e0.y, 1) DOTD(e0.z, 2) DOTD(e0.w, 3)
            DOTD(e1.x, 4)  DOTD(e1.y, 5) DOTD(e1.z, 6) DOTD(e1.w, 7)
            #undef DOTD
            #undef DOTD0

            // scale by own span's factor, then select-free XOR butterfly fold (all DPP)
            float e_own = __expf(ms_j - ms_w);
            float f0 = (float)ac0 * e_own, f1 = (float)ac1 * e_own;
            float f2 = (float)ac2 * e_own, f3 = (float)ac3 * e_own;
            float f4 = (float)ac4 * e_own, f5 = (float)ac5 * e_own;
            float f6 = (float)ac6 * e_own, f7 = (float)ac7 * e_own;
            f0 = fxaddf<0xB1>(f0, f1);  f2 = fxaddf<0xB1>(f2, f3);
            f4 = fxaddf<0xB1>(f4, f5);  f6 = fxaddf<0xB1>(f6, f7);
            f0 = fxaddf<0x4E>(f0, f2);  f4 = fxaddf<0x4E>(f4, f6);
            f0 = fxaddf<0x124>(f0, f4); // xor4 via DPP (proven on gfx950 by R2)

            // linear tail: Kv = f0*E; exact wave max; un = 15*Kv/K (<=15 by constr.)
            float Kv = f0 * EA;
            float K = wavemax_fast(Kv);
            un = __float2int_rn(15.f * Kv * __builtin_amdgcn_rcpf(K));
            NPACK(un, cur ^ 1)
            ms_w = ms_w + __logf(K) - LN120;     // product scale 8*15 = 120
            if (l == 0) Ms[cur ^ 1][w] = ms_w;
            EA = EB; EB = EN;
            barrier_lds();              // single barrier/step, LDS-drain only
            cur ^= 1;
        }
        #undef NPACK

        // final: alpha(s) = log(u_s/15) + Ms[w(s)]
        float mm = Ms[cur][0];
        #pragma unroll
        for (int k2 = 1; k2 < 8; ++k2) mm = fmaxf(mm, Ms[cur][k2]);
        float fv = (float)un * __expf(den_final[tid] + (ms_w - mm));
        fv = waveallsum(fv);
        if (l == 0) fr[w] = fv;
        __syncthreads();
        if (tid == 0) {
            float tot = 0.f;
            for (int i = 0; i < 8; ++i) tot += fr[i];
            parts[B_ + b] = mm + __logf(tot) - LNU;
        }
    } else {
        // ---- numerator: 4 banded 128-state chains per 512-thread WG
        //      (R1-proven path; double-buffered -> 1 barrier/step) ----
        __shared__ float aLn[2][4][SN_];
        __shared__ float nredn[4][2];
        const int nb = blockIdx.x - B_;               // 0..7
        const int lb = tid >> 7;                      // local batch 0..3
        const int b  = nb * 4 + lb;
        const int s  = tid & 127;
        const int L  = seqlen[b];
        const int lane = tid & 63;
        const int wv2 = (tid >> 6) & 1;
        const float* ep = em_num + (size_t)b * T_ * SN_ + s;
        const float tself = num_trans[((size_t)b * SN_ + s) * SN_ + s];
        const float tup = (s > 0) ? num_trans[((size_t)b * SN_ + (s - 1)) * SN_ + s] : 0.f;
        float alpha = num_init[b * SN_ + s] + ep[0];
        aLn[0][lb][s] = alpha;
        __syncthreads();
        float emA = ep[SN_], emB = ep[2 * SN_];
        int cur = 0;
        for (int t = 1; t < T_; ++t) {
            int tt = t + 2; if (tt > T_ - 1) tt = T_ - 1;
            float emN = ep[(size_t)tt * SN_];
            bool live = (t < L);
            float yy = alpha + tself;
            float newa;
            if (s > 0) {
                float xx = aLn[cur][lb][s - 1] + tup;
                float mx = fmaxf(xx, yy), mn = fminf(xx, yy);
                newa = mx + log1pf(__expf(mn - mx)) + emA;
            } else {
                newa = yy + emA;
            }
            if (live) alpha = newa;
            aLn[cur ^ 1][lb][s] = alpha;
            emA = emB; emB = emN;
            __syncthreads();
            cur ^= 1;
        }
        float v = alpha + num_final[b * SN_ + s];
        float wm = v;
        #pragma unroll
        for (int o = 32; o; o >>= 1) wm = fmaxf(wm, __shfl_xor(wm, o, 64));
        if (lane == 0) nredn[lb][wv2] = wm;
        __syncthreads();
        float fm = fmaxf(nredn[lb][0], nredn[lb][1]);
        __syncthreads();
        float pe = __expf(v - fm);
        #pragma unroll
        for (int o = 32; o; o >>= 1) pe += __shfl_xor(pe, o, 64);
        if (lane == 0) nredn[lb][wv2] = pe;
        __syncthreads();
        if (s == 0) parts[b] = fm + __logf(nredn[lb][0] + nredn[lb][1]);
    }
}

__global__ void finish(const float* __restrict__ parts, float* __restrict__ out) {
    int lane = threadIdx.x;   // 64 threads, 1 wave
    float v = (lane < B_) ? (parts[B_ + lane] - parts[lane]) : 0.f;
    #pragma unroll
    for (int o = 32; o; o >>= 1) v += __shfl_xor(v, o, 64);
    if (lane == 0) out[0] = v;   // loss = sum(den) - sum(num)
}

extern "C" void kernel_launch(void* const* d_in, const int* in_sizes, int n_in,
                              void* d_out, int out_size, void* d_ws, size_t ws_size,
                              hipStream_t stream) {
    const float* x         = (const float*)d_in[0];
    const int*   seqlen    = (const int*)d_in[1];
    const float* num_trans = (const float*)d_in[2];
    const int*   num_pdf   = (const int*)d_in[3];
    const float* num_init  = (const float*)d_in[4];
    const float* num_final = (const float*)d_in[5];
    const float* den_trans = (const float*)d_in[6];
    const int*   den_pdf   = (const int*)d_in[7];
    const float* den_init  = (const float*)d_in[8];
    const float* den_final = (const float*)d_in[9];
    float* out   = (float*)d_out;
    float* parts = (float*)d_ws;                                  // 64 floats
    unsigned* tp8 = (unsigned*)((char*)d_ws + 4096);              // 128 KB u4 packed trans
    float* em_den = (float*)((char*)d_ws + 4096 + 131072);        // 26.2 MB (linear E)
    float* em_num = em_den + 6553600;                             // 6.5 MB

    prep<<<8032, 1024, 0, stream>>>(den_trans, tp8, x, den_pdf, num_pdf, em_den, em_num);
    fwd_kernel<<<40, 512, 0, stream>>>(seqlen, num_trans, num_init, num_final,
                                       tp8, den_init, den_final, em_den, em_num, parts);
    finish<<<1, 64, 0, stream>>>(parts, out);
}